// Round 13
// baseline (166.579 us; speedup 1.0000x reference)
//
#include <hip/hip_runtime.h>
#include <float.h>

#define B_ 4
#define C_ 64
#define N_ 4096
#define O_ 64
#define K_ 20
#define EPS_ 1e-5f

typedef float f32x4 __attribute__((ext_vector_type(4)));
typedef short s16x8 __attribute__((ext_vector_type(8)));

union Frag { uint4 u; s16x8 s; };

// ws layout (in float slots)
#define OFF_XX   ((size_t)0)              // 16384
#define OFF_A    ((size_t)16384)          // 1048576
#define OFF_CC   ((size_t)1064960)        // 1048576
#define OFF_YMAX ((size_t)2113536)        // 1048576  (xt lives here until k_l2m5)
#define OFF_YMIN ((size_t)3162112)        // 1048576  (Phi lives here until k_l2m5)
#define OFF_SUMS ((size_t)4210688)        // 256
#define OFF_IDX  ((size_t)4211200)        // 327680 ints
#define OFF_XT   OFF_YMAX
#define OFF_PHI  OFF_YMIN

__device__ inline ushort f2bf(float f) {
  uint u = __float_as_uint(f);
  return (ushort)((u + 0x7fffu + ((u >> 16) & 1u)) >> 16);
}
__device__ inline float bf2f(ushort h) { return __uint_as_float(((uint)h) << 16); }

// ------ K0: fused prep: xx, xt, Phi, A, Cc from one x read ------------
__global__ __launch_bounds__(256) void k_prep(const float* __restrict__ x,
                                              const float* __restrict__ w1,
                                              float* __restrict__ xx,
                                              float* __restrict__ xt,
                                              ushort* __restrict__ Phi,
                                              float* __restrict__ A,
                                              float* __restrict__ Cc) {
  __shared__ float lds[64 * 65];
  __shared__ ushort ldsW[32 * 512];
  const int tid = threadIdx.x;
  const int lane = tid & 63, w = tid >> 6;
  const int b = blockIdx.x >> 6;
  const int n0 = (blockIdx.x & 63) << 6;
  const int bN = b << 12;

  {
    const int nl = tid & 63;
    const int rbase = (tid >> 6) * 16;
#pragma unroll
    for (int r = 0; r < 16; ++r) {
      int c = rbase + r;
      lds[c * 65 + nl] = x[((size_t)(b * 64 + c)) * N_ + n0 + nl];
    }
  }
  __syncthreads();

  {
    int p = tid >> 2, c0 = (tid & 3) << 4;
#pragma unroll
    for (int q = 0; q < 4; ++q) {
      float4 v;
      v.x = lds[(c0 + q * 4 + 0) * 65 + p];
      v.y = lds[(c0 + q * 4 + 1) * 65 + p];
      v.z = lds[(c0 + q * 4 + 2) * 65 + p];
      v.w = lds[(c0 + q * 4 + 3) * 65 + p];
      *(float4*)(xt + ((size_t)(bN + n0 + p)) * 64 + c0 + q * 4) = v;
    }
  }

  Frag xph[2], xpl[2];
  {
    const int nloc = w * 16 + (lane & 15);
    const int gnt = (n0 >> 4) + w;
#pragma unroll
    for (int kt = 0; kt < 2; ++kt) {
      int cbase = kt * 32 + ((lane >> 4) << 3);
      ushort hi[8], lo[8];
#pragma unroll
      for (int e = 0; e < 8; ++e) {
        float v = lds[(cbase + e) * 65 + nloc];
        ushort h = f2bf(v);
        float l = v - bf2f(h);
        hi[e] = h;
        lo[e] = f2bf(l);
      }
      size_t base = ((size_t)((b * 256 + gnt) * 2 + kt)) * 512 + lane * 8;
      uint4 uh, ul;
      uh.x = hi[0] | ((uint)hi[1] << 16); uh.y = hi[2] | ((uint)hi[3] << 16);
      uh.z = hi[4] | ((uint)hi[5] << 16); uh.w = hi[6] | ((uint)hi[7] << 16);
      ul.x = lo[0] | ((uint)lo[1] << 16); ul.y = lo[2] | ((uint)lo[3] << 16);
      ul.z = lo[4] | ((uint)lo[5] << 16); ul.w = lo[6] | ((uint)lo[7] << 16);
      *(uint4*)(Phi + base) = uh;
      xph[kt].u = uh;
      xpl[kt].u = ul;
    }
  }

  {
    const int l = tid & 63;
    const int sel = tid >> 6, mat = sel & 1, kt = sel >> 1;
#pragma unroll
    for (int ot = 0; ot < 4; ++ot) {
      const int o = ot * 16 + (l & 15);
      uint hw[8], lw[8];
#pragma unroll
      for (int e = 0; e < 8; ++e) {
        int c = kt * 32 + (l >> 4) * 8 + e;
        float wa = w1[o * 128 + c];
        float v = mat ? (w1[o * 128 + 64 + c] - wa) : wa;
        ushort hb = f2bf(v);
        float lv = v - bf2f(hb);
        hw[e] = hb;
        lw[e] = f2bf(lv);
      }
      uint4 uh, ul;
      uh.x = hw[0] | (hw[1] << 16); uh.y = hw[2] | (hw[3] << 16);
      uh.z = hw[4] | (hw[5] << 16); uh.w = hw[6] | (hw[7] << 16);
      ul.x = lw[0] | (lw[1] << 16); ul.y = lw[2] | (lw[3] << 16);
      ul.z = lw[4] | (lw[5] << 16); ul.w = lw[6] | (lw[7] << 16);
      int fb = (mat * 4 + ot) * 4 + kt * 2;
      *(uint4*)(&ldsW[(size_t)(fb + 0) * 512 + l * 8]) = uh;
      *(uint4*)(&ldsW[(size_t)(fb + 1) * 512 + l * 8]) = ul;
    }
  }

  if (tid < 64) {
    float acc = 0.f;
#pragma unroll
    for (int c = 0; c < 64; ++c) {
      float v = lds[c * 65 + tid];
      acc = fmaf(v, v, acc);
    }
    xx[bN + n0 + tid] = acc;
  }
  __syncthreads();

#pragma unroll
  for (int mat = 0; mat < 2; ++mat) {
    float* outp = mat ? Cc : A;
#pragma unroll
    for (int ot = 0; ot < 4; ++ot) {
      int fb = (mat * 4 + ot) * 4;
      Frag bh0, bl0, bh1, bl1;
      bh0.u = *(const uint4*)(&ldsW[(size_t)(fb + 0) * 512 + lane * 8]);
      bl0.u = *(const uint4*)(&ldsW[(size_t)(fb + 1) * 512 + lane * 8]);
      bh1.u = *(const uint4*)(&ldsW[(size_t)(fb + 2) * 512 + lane * 8]);
      bl1.u = *(const uint4*)(&ldsW[(size_t)(fb + 3) * 512 + lane * 8]);
      f32x4 acc = {0.f, 0.f, 0.f, 0.f};
      acc = __builtin_amdgcn_mfma_f32_16x16x32_bf16(xph[0].s, bh0.s, acc, 0, 0, 0);
      acc = __builtin_amdgcn_mfma_f32_16x16x32_bf16(xph[1].s, bh1.s, acc, 0, 0, 0);
      acc = __builtin_amdgcn_mfma_f32_16x16x32_bf16(xph[0].s, bl0.s, acc, 0, 0, 0);
      acc = __builtin_amdgcn_mfma_f32_16x16x32_bf16(xph[1].s, bl1.s, acc, 0, 0, 0);
      acc = __builtin_amdgcn_mfma_f32_16x16x32_bf16(xpl[0].s, bh0.s, acc, 0, 0, 0);
      acc = __builtin_amdgcn_mfma_f32_16x16x32_bf16(xpl[1].s, bh1.s, acc, 0, 0, 0);
#pragma unroll
      for (int r = 0; r < 4; ++r) {
        int ploc = w * 16 + ((lane >> 4) << 2) + r;
        outp[(size_t)(bN + n0 + ploc) * 64 + ot * 16 + (lane & 15)] = acc[r];
      }
    }
  }
}

// ------ K1: kNN. Hi-only both passes (margin 2.0), depth-3 pipelines,
// XCD swizzle, exact fp32 refine, fused BN1 stats. 512 blocks x 512 thr.
// (round-10 proven version, verbatim)
__global__ __launch_bounds__(512, 4) void k_knn8(
    const ushort* __restrict__ Phi,
    const float* __restrict__ xx, const float* __restrict__ xt,
    const float* __restrict__ A, const float* __restrict__ Cc,
    const float* __restrict__ b1, int* __restrict__ idxout,
    float* __restrict__ sums) {
  __shared__ float pool[4096];
  __shared__ float xxi[32];
  __shared__ float Tsh[32];
  __shared__ uint  cnt[32];
  __shared__ int   cand[32 * 64];

  const int tid = threadIdx.x;
  const int lane = tid & 63, w = tid >> 6;
  const int col = lane & 15, g4 = (lane >> 4) << 2;
  const int obid = (blockIdx.x & 7) * 64 + (blockIdx.x >> 3);
  const int b = obid >> 7;
  const int i0 = (obid & 127) << 5;
  const int bN = b << 12;
  if (tid < 32) { xxi[tid] = xx[bN + i0 + tid]; cnt[tid] = 0; }

  const ushort* Pb = Phi + (size_t)b * 262144 + lane * 8;
  const float*  xb = xx + bN + col;

  Frag ahi[2][2];
#pragma unroll
  for (int isub = 0; isub < 2; ++isub) {
    int nt = (i0 >> 4) + isub;
#pragma unroll
    for (int kt = 0; kt < 2; ++kt)
      ahi[isub][kt].u = *(const uint4*)(Phi + ((size_t)((b * 256 + nt) * 2 + kt)) * 512 + lane * 8);
  }
  float xxr[8];
#pragma unroll
  for (int isub = 0; isub < 2; ++isub)
#pragma unroll
    for (int r = 0; r < 4; ++r)
      xxr[isub * 4 + r] = xx[bN + i0 + isub * 16 + g4 + r];

  struct BT { Frag h0, h1; float xxj; };

  float c1[8];
#pragma unroll
  for (int r = 0; r < 8; ++r) c1[r] = FLT_MAX;

  auto hi0 = [&](const BT& t) {
    __builtin_amdgcn_s_setprio(1);
#pragma unroll
    for (int isub = 0; isub < 2; ++isub) {
      f32x4 acc = {0.f, 0.f, 0.f, 0.f};
      acc = __builtin_amdgcn_mfma_f32_16x16x32_bf16(ahi[isub][0].s, t.h0.s, acc, 0, 0, 0);
      acc = __builtin_amdgcn_mfma_f32_16x16x32_bf16(ahi[isub][1].s, t.h1.s, acc, 0, 0, 0);
#pragma unroll
      for (int r = 0; r < 4; ++r) {
        float d = fmaf(-2.f, acc[r], xxr[isub * 4 + r]) + t.xxj;
        c1[isub * 4 + r] = fminf(c1[isub * 4 + r], d);
      }
    }
    __builtin_amdgcn_s_setprio(0);
  };

  {
    const ushort* p0 = Pb + (size_t)w * 1024;
    const ushort* p1 = p0 + 8192;
    const ushort* p2 = p0 + 16384;
    const float* x0 = xb + w * 16;
    const float* x1 = x0 + 128;
    const float* x2 = x0 + 256;
    BT t0, t1, t2;
    t0.h0.u = *(const uint4*)(p0); t0.h1.u = *(const uint4*)(p0 + 512); t0.xxj = *x0;
    t1.h0.u = *(const uint4*)(p1); t1.h1.u = *(const uint4*)(p1 + 512); t1.xxj = *x1;
    t2.h0.u = *(const uint4*)(p2); t2.h1.u = *(const uint4*)(p2 + 512); t2.xxj = *x2;
    for (int g = 0; g < 10; ++g) {
      hi0(t0);
      p0 += 24576; x0 += 384;
      t0.h0.u = *(const uint4*)(p0); t0.h1.u = *(const uint4*)(p0 + 512); t0.xxj = *x0;
      hi0(t1);
      p1 += 24576; x1 += 384;
      t1.h0.u = *(const uint4*)(p1); t1.h1.u = *(const uint4*)(p1 + 512); t1.xxj = *x1;
      hi0(t2);
      p2 += 24576; x2 += 384;
      if (g < 9) { t2.h0.u = *(const uint4*)(p2); t2.h1.u = *(const uint4*)(p2 + 512); t2.xxj = *x2; }
    }
    hi0(t0);   // s = 30
    hi0(t1);   // s = 31
  }
#pragma unroll
  for (int isub = 0; isub < 2; ++isub)
#pragma unroll
    for (int r = 0; r < 4; ++r)
      pool[(isub * 16 + g4 + r) * 128 + w * 16 + col] = c1[isub * 4 + r];
  __syncthreads();

  // threshold: 20-round min-pop over 128 cell minima (4 rows/wave).
  // margin 2.0 covers 2x hi-only err (each <= ~2*2^-8*|xi||xj| <= ~0.96)
#pragma unroll
  for (int rr = 0; rr < 4; ++rr) {
    const int row = w * 4 + rr;
    float lo = pool[row * 128 + lane];
    float hi = pool[row * 128 + 64 + lane];
    float a = fminf(lo, hi);
    hi = fmaxf(lo, hi);
    lo = a;
    float m = 0.f;
    for (int t = 0; t < 20; ++t) {
      m = lo;
#pragma unroll
      for (int mm = 1; mm < 64; mm <<= 1) m = fminf(m, __shfl_xor(m, mm, 64));
      if (lo == m) { lo = hi; hi = FLT_MAX; }
    }
    if (lane == 0) Tsh[row] = m + 2.0f;
  }
  __syncthreads();
  float tr[8];
#pragma unroll
  for (int isub = 0; isub < 2; ++isub)
#pragma unroll
    for (int r = 0; r < 4; ++r) tr[isub * 4 + r] = Tsh[isub * 16 + g4 + r];

  auto comp1 = [&](int js, const BT& t) {
    const int jme = js * 16 + col;
    __builtin_amdgcn_s_setprio(1);
#pragma unroll
    for (int isub = 0; isub < 2; ++isub) {
      f32x4 acc = {0.f, 0.f, 0.f, 0.f};
      acc = __builtin_amdgcn_mfma_f32_16x16x32_bf16(ahi[isub][0].s, t.h0.s, acc, 0, 0, 0);
      acc = __builtin_amdgcn_mfma_f32_16x16x32_bf16(ahi[isub][1].s, t.h1.s, acc, 0, 0, 0);
#pragma unroll
      for (int r = 0; r < 4; ++r) {
        float d = fmaf(-2.f, acc[r], xxr[isub * 4 + r]) + t.xxj;
        if (d <= tr[isub * 4 + r]) {
          int row = isub * 16 + g4 + r;
          uint pos = atomicAdd(&cnt[row], 1u);
          if (pos < 64) cand[row * 64 + pos] = jme;
        }
      }
    }
    __builtin_amdgcn_s_setprio(0);
  };
  {
    const ushort* p0 = Pb + (size_t)w * 1024;
    const ushort* p1 = p0 + 8192;
    const ushort* p2 = p0 + 16384;
    const float* x0 = xb + w * 16;
    const float* x1 = x0 + 128;
    const float* x2 = x0 + 256;
    BT t0, t1, t2;
    t0.h0.u = *(const uint4*)(p0); t0.h1.u = *(const uint4*)(p0 + 512); t0.xxj = *x0;
    t1.h0.u = *(const uint4*)(p1); t1.h1.u = *(const uint4*)(p1 + 512); t1.xxj = *x1;
    t2.h0.u = *(const uint4*)(p2); t2.h1.u = *(const uint4*)(p2 + 512); t2.xxj = *x2;
    int js0 = w, js1 = w + 8, js2 = w + 16;
    for (int g = 0; g < 10; ++g) {
      comp1(js0, t0);
      js0 += 24; p0 += 24576; x0 += 384;
      t0.h0.u = *(const uint4*)(p0); t0.h1.u = *(const uint4*)(p0 + 512); t0.xxj = *x0;
      comp1(js1, t1);
      js1 += 24; p1 += 24576; x1 += 384;
      t1.h0.u = *(const uint4*)(p1); t1.h1.u = *(const uint4*)(p1 + 512); t1.xxj = *x1;
      comp1(js2, t2);
      js2 += 24; p2 += 24576; x2 += 384;
      if (g < 9) { t2.h0.u = *(const uint4*)(p2); t2.h1.u = *(const uint4*)(p2 + 512); t2.xxj = *x2; }
    }
    comp1(js0, t0);   // s = 30
    comp1(js1, t1);   // s = 31
  }
  __syncthreads();

  // ---------- exact fp32 refine + bitonic top-20 + fused BN1 stats --------
  const float b1r = b1[lane];
  float s = 0.f, ssq = 0.f;
  for (int rr = 0; rr < 4; ++rr) {
    const int row = w * 4 + rr;
    const int nc = (int)min(cnt[row], 64u);
    unsigned long long key = ~0ULL;
    if (lane < nc) {
      int j = cand[row * 64 + lane];
      const float* xj = xt + ((size_t)bN + j) * 64;
      const float* xic = xt + ((size_t)bN + i0 + row) * 64;
      float dot = 0.f;
#pragma unroll 8
      for (int c = 0; c < 64; ++c) dot = fmaf(xic[c], xj[c], dot);
      float dex = (xxi[row] - 2.f * dot) + xx[bN + j];
      uint fb = __float_as_uint(dex);
      fb = (fb & 0x80000000u) ? ~fb : (fb | 0x80000000u);
      key = (((unsigned long long)fb) << 32) | (uint)j;
    }
#pragma unroll
    for (int k2 = 2; k2 <= 64; k2 <<= 1) {
#pragma unroll
      for (int mm = k2 >> 1; mm >= 1; mm >>= 1) {
        uint klo = (uint)key, khi = (uint)(key >> 32);
        uint olo = __shfl_xor((int)klo, mm, 64);
        uint ohi = __shfl_xor((int)khi, mm, 64);
        unsigned long long o = (((unsigned long long)ohi) << 32) | olo;
        bool up = ((lane & k2) == 0);
        bool lowhalf = ((lane & mm) == 0);
        bool keepmin = (up == lowhalf);
        key = keepmin ? (key < o ? key : o) : (key > o ? key : o);
      }
    }
    int myj = (int)(uint)key;
    if (lane < 20) idxout[((size_t)bN + i0 + row) * 20 + lane] = myj;

    float ccv = Cc[((size_t)bN + i0 + row) * 64 + lane] + b1r;
    int jk[20];
#pragma unroll
    for (int k = 0; k < 20; ++k) jk[k] = __shfl(myj, k, 64);
    float av[20];
#pragma unroll
    for (int k = 0; k < 20; ++k) av[k] = A[((size_t)bN + jk[k]) * 64 + lane];
#pragma unroll
    for (int k = 0; k < 20; ++k) {
      float v = av[k] + ccv;
      s += v;
      ssq = fmaf(v, v, ssq);
    }
  }
  __syncthreads();
  pool[w * 64 + lane] = s;
  pool[512 + w * 64 + lane] = ssq;
  __syncthreads();
  if (tid < 64) {
    float S = 0.f, Q = 0.f;
#pragma unroll
    for (int q = 0; q < 8; ++q) {
      S += pool[q * 64 + tid];
      Q += pool[512 + q * 64 + tid];
    }
    atomicAdd(&sums[tid], S);
    atomicAdd(&sums[64 + tid], Q);
  }
}

// ------ K5: MFMA layer-2 with fin1 folded in (per-block ST1 + w2 pack).
// 512 blocks x 256 thr, 8 pts/wave, XCD swizzle.
__global__ __launch_bounds__(256, 2) void k_l2m5(
    const float* __restrict__ A, const float* __restrict__ Cc,
    const int* __restrict__ idx, const float* __restrict__ sums,
    const float* __restrict__ b1, const float* __restrict__ g1,
    const float* __restrict__ be1, const float* __restrict__ w2,
    const float* __restrict__ b2,
    float* __restrict__ ymax, float* __restrict__ ymin,
    float* __restrict__ sums2) {
  __shared__ float red2[512];
  __shared__ float st1sh[128];
  const int tid = threadIdx.x;
  const int lane = tid & 63, w = tid >> 6;
  const int g = lane >> 4, col = lane & 15;
  const int obid = (blockIdx.x & 7) * 64 + (blockIdx.x >> 3);

  // fin1 folded: BN1 scale/shift from sums (complete after k_knn8 kernel)
  if (tid < 64) {
    const float E = 327680.f;
    float m = sums[tid] / E;
    float var = fmaxf(sums[64 + tid] / E - m * m, 0.f);
    float sc = g1[tid] / sqrtf(var + EPS_);
    st1sh[tid] = sc;
    st1sh[64 + tid] = be1[tid] + (b1[tid] - m) * sc;
  }

  // per-lane w2 fragment pack (replaces w2p global)
  Frag wh[4][2], wl[4][2];
#pragma unroll
  for (int ot = 0; ot < 4; ++ot) {
#pragma unroll
    for (int kt = 0; kt < 2; ++kt) {
      const float* wr = w2 + (ot * 16 + col) * 64 + kt * 32 + g * 8;
      float4 v0 = *(const float4*)(wr);
      float4 v1 = *(const float4*)(wr + 4);
      float vv[8] = {v0.x, v0.y, v0.z, v0.w, v1.x, v1.y, v1.z, v1.w};
      uint hw[8], lw[8];
#pragma unroll
      for (int e = 0; e < 8; ++e) {
        ushort hb = f2bf(vv[e]);
        hw[e] = hb;
        lw[e] = f2bf(vv[e] - bf2f(hb));
      }
      uint4 uh, ul;
      uh.x = hw[0] | (hw[1] << 16); uh.y = hw[2] | (hw[3] << 16);
      uh.z = hw[4] | (hw[5] << 16); uh.w = hw[6] | (hw[7] << 16);
      ul.x = lw[0] | (lw[1] << 16); ul.y = lw[2] | (lw[3] << 16);
      ul.z = lw[4] | (lw[5] << 16); ul.w = lw[6] | (lw[7] << 16);
      wh[ot][kt].u = uh;
      wl[ot][kt].u = ul;
    }
  }
  __syncthreads();

  float S1v[2][8], T1v[2][8];
#pragma unroll
  for (int kt = 0; kt < 2; ++kt) {
    int c0 = kt * 32 + g * 8;
#pragma unroll
    for (int e = 0; e < 8; ++e) {
      S1v[kt][e] = st1sh[c0 + e];
      T1v[kt][e] = st1sh[64 + c0 + e];
    }
  }
  float b2r[4];
#pragma unroll
  for (int ot = 0; ot < 4; ++ot) b2r[ot] = b2[ot * 16 + col];

  float ps[4] = {0.f, 0.f, 0.f, 0.f}, pss[4] = {0.f, 0.f, 0.f, 0.f};

  for (int rep = 0; rep < 4; ++rep) {
    const int p0 = ((obid * 4 + w) * 4 + rep) * 2;
    const int bbase = (p0 >> 12) << 12;

    Frag hh[2][2][2];
#pragma unroll
    for (int pt = 0; pt < 2; ++pt) {
      const int p = p0 + pt;
      const float* Cp = Cc + (size_t)p * 64;
#pragma unroll
      for (int t = 0; t < 2; ++t) {
        int kk = t * 16 + col;
        kk = kk > 19 ? 19 : kk;
        int j = idx[p * 20 + kk];
        const float* Ap = A + ((size_t)(bbase + j)) * 64;
#pragma unroll
        for (int kt = 0; kt < 2; ++kt) {
          int c0 = kt * 32 + g * 8;
          float4 a0 = *(const float4*)(Ap + c0);
          float4 a1 = *(const float4*)(Ap + c0 + 4);
          float4 q0 = *(const float4*)(Cp + c0);
          float4 q1 = *(const float4*)(Cp + c0 + 4);
          float hv[8];
          hv[0] = fmaxf(0.f, fmaf(a0.x + q0.x, S1v[kt][0], T1v[kt][0]));
          hv[1] = fmaxf(0.f, fmaf(a0.y + q0.y, S1v[kt][1], T1v[kt][1]));
          hv[2] = fmaxf(0.f, fmaf(a0.z + q0.z, S1v[kt][2], T1v[kt][2]));
          hv[3] = fmaxf(0.f, fmaf(a0.w + q0.w, S1v[kt][3], T1v[kt][3]));
          hv[4] = fmaxf(0.f, fmaf(a1.x + q1.x, S1v[kt][4], T1v[kt][4]));
          hv[5] = fmaxf(0.f, fmaf(a1.y + q1.y, S1v[kt][5], T1v[kt][5]));
          hv[6] = fmaxf(0.f, fmaf(a1.z + q1.z, S1v[kt][6], T1v[kt][6]));
          hv[7] = fmaxf(0.f, fmaf(a1.w + q1.w, S1v[kt][7], T1v[kt][7]));
          uint4 uh;
          uh.x = f2bf(hv[0]) | ((uint)f2bf(hv[1]) << 16);
          uh.y = f2bf(hv[2]) | ((uint)f2bf(hv[3]) << 16);
          uh.z = f2bf(hv[4]) | ((uint)f2bf(hv[5]) << 16);
          uh.w = f2bf(hv[6]) | ((uint)f2bf(hv[7]) << 16);
          hh[pt][t][kt].u = uh;
        }
      }
    }

    float mx[2][4], mn[2][4];
#pragma unroll
    for (int pt = 0; pt < 2; ++pt)
#pragma unroll
      for (int ot = 0; ot < 4; ++ot) { mx[pt][ot] = -FLT_MAX; mn[pt][ot] = FLT_MAX; }

    __builtin_amdgcn_s_setprio(1);
#pragma unroll
    for (int ot = 0; ot < 4; ++ot) {
#pragma unroll
      for (int pt = 0; pt < 2; ++pt) {
        f32x4 accA = {0.f, 0.f, 0.f, 0.f};
        accA = __builtin_amdgcn_mfma_f32_16x16x32_bf16(hh[pt][0][0].s, wh[ot][0].s, accA, 0, 0, 0);
        accA = __builtin_amdgcn_mfma_f32_16x16x32_bf16(hh[pt][0][1].s, wh[ot][1].s, accA, 0, 0, 0);
        accA = __builtin_amdgcn_mfma_f32_16x16x32_bf16(hh[pt][0][0].s, wl[ot][0].s, accA, 0, 0, 0);
        accA = __builtin_amdgcn_mfma_f32_16x16x32_bf16(hh[pt][0][1].s, wl[ot][1].s, accA, 0, 0, 0);
        f32x4 accB = {0.f, 0.f, 0.f, 0.f};
        accB = __builtin_amdgcn_mfma_f32_16x16x32_bf16(hh[pt][1][0].s, wh[ot][0].s, accB, 0, 0, 0);
        accB = __builtin_amdgcn_mfma_f32_16x16x32_bf16(hh[pt][1][1].s, wh[ot][1].s, accB, 0, 0, 0);
        accB = __builtin_amdgcn_mfma_f32_16x16x32_bf16(hh[pt][1][0].s, wl[ot][0].s, accB, 0, 0, 0);
        accB = __builtin_amdgcn_mfma_f32_16x16x32_bf16(hh[pt][1][1].s, wl[ot][1].s, accB, 0, 0, 0);
#pragma unroll
        for (int r = 0; r < 4; ++r) {
          float y = accA[r] + b2r[ot];
          mx[pt][ot] = fmaxf(mx[pt][ot], y);
          mn[pt][ot] = fminf(mn[pt][ot], y);
          ps[ot] += y;
          pss[ot] = fmaf(y, y, pss[ot]);
        }
        if (g == 0) {
#pragma unroll
          for (int r = 0; r < 4; ++r) {
            float y = accB[r] + b2r[ot];
            mx[pt][ot] = fmaxf(mx[pt][ot], y);
            mn[pt][ot] = fminf(mn[pt][ot], y);
            ps[ot] += y;
            pss[ot] = fmaf(y, y, pss[ot]);
          }
        }
      }
    }
    __builtin_amdgcn_s_setprio(0);

#pragma unroll
    for (int pt = 0; pt < 2; ++pt) {
#pragma unroll
      for (int ot = 0; ot < 4; ++ot) {
        float v = mx[pt][ot];
        v = fmaxf(v, __shfl_xor(v, 16, 64));
        v = fmaxf(v, __shfl_xor(v, 32, 64));
        mx[pt][ot] = v;
        float u = mn[pt][ot];
        u = fminf(u, __shfl_xor(u, 16, 64));
        u = fminf(u, __shfl_xor(u, 32, 64));
        mn[pt][ot] = u;
      }
      float wmx = mx[pt][0], wmn = mn[pt][0];
      if (g == 1) { wmx = mx[pt][1]; wmn = mn[pt][1]; }
      if (g == 2) { wmx = mx[pt][2]; wmn = mn[pt][2]; }
      if (g == 3) { wmx = mx[pt][3]; wmn = mn[pt][3]; }
      ymax[(size_t)(p0 + pt) * 64 + lane] = wmx;
      ymin[(size_t)(p0 + pt) * 64 + lane] = wmn;
    }
  }

#pragma unroll
  for (int ot = 0; ot < 4; ++ot) {
    float s = ps[ot];
    s += __shfl_xor(s, 16, 64);
    s += __shfl_xor(s, 32, 64);
    ps[ot] = s;
    float q = pss[ot];
    q += __shfl_xor(q, 16, 64);
    q += __shfl_xor(q, 32, 64);
    pss[ot] = q;
  }
  float sv = ps[0], qv = pss[0];
  if (g == 1) { sv = ps[1]; qv = pss[1]; }
  if (g == 2) { sv = ps[2]; qv = pss[2]; }
  if (g == 3) { sv = ps[3]; qv = pss[3]; }
  red2[w * 64 + lane] = sv;
  red2[256 + w * 64 + lane] = qv;
  __syncthreads();
  if (tid < 64) {
    float S = red2[tid] + red2[64 + tid] + red2[128 + tid] + red2[192 + tid];
    float Q = red2[256 + tid] + red2[320 + tid] + red2[384 + tid] + red2[448 + tid];
    atomicAdd(&sums2[tid], S);
    atomicAdd(&sums2[64 + tid], Q);
  }
}

// ------ K6: epilogue with fin2 folded in + LDS transpose ------------------
__global__ __launch_bounds__(256) void k_out2(const float* __restrict__ ymax,
                                              const float* __restrict__ ymin,
                                              const float* __restrict__ sums2,
                                              const float* __restrict__ g2,
                                              const float* __restrict__ be2,
                                              float* __restrict__ out) {
  __shared__ float tl[64 * 65];
  const int tid = threadIdx.x;
  const int b = blockIdx.x >> 6;
  const int n0 = (blockIdx.x & 63) << 6;
  {
    const int o = tid & 63, pr = tid >> 6;
    // fin2 folded: BN2 scale/shift from sums2 (complete after k_l2m5 kernel)
    const float E = 327680.f;
    float m = sums2[o] / E;
    float var = fmaxf(sums2[64 + o] / E - m * m, 0.f);
    float s = g2[o] / sqrtf(var + EPS_);
    float tt = be2[o] - m * s;
#pragma unroll
    for (int q = 0; q < 16; ++q) {
      int pl = pr + q * 4;
      size_t p = ((size_t)(b << 12)) + n0 + pl;
      float vmax = ymax[p * 64 + o];
      float vmin = ymin[p * 64 + o];
      float v = (s >= 0.f) ? vmax : vmin;
      tl[o * 65 + pl] = fmaxf(0.f, fmaf(v, s, tt));
    }
  }
  __syncthreads();
  {
    const int nl = tid & 63, orow = tid >> 6;
#pragma unroll
    for (int q = 0; q < 16; ++q) {
      int oo = orow + q * 4;
      out[((size_t)(b * 64 + oo)) * N_ + n0 + nl] = tl[oo * 65 + nl];
    }
  }
}

extern "C" void kernel_launch(void* const* d_in, const int* in_sizes, int n_in,
                              void* d_out, int out_size, void* d_ws, size_t ws_size,
                              hipStream_t stream) {
  const float* x   = (const float*)d_in[0];
  const float* w1  = (const float*)d_in[1];
  const float* b1  = (const float*)d_in[2];
  const float* g1  = (const float*)d_in[3];
  const float* be1 = (const float*)d_in[4];
  const float* w2  = (const float*)d_in[5];
  const float* b2  = (const float*)d_in[6];
  const float* g2  = (const float*)d_in[7];
  const float* be2 = (const float*)d_in[8];
  float* out = (float*)d_out;
  float* ws = (float*)d_ws;

  float* xx   = ws + OFF_XX;
  float* A    = ws + OFF_A;
  float* Cc   = ws + OFF_CC;
  float* ymax = ws + OFF_YMAX;
  float* ymin = ws + OFF_YMIN;
  float* sums = ws + OFF_SUMS;   // [sum1|sumsq1|sum2|sumsq2], 256 floats
  int*   idx  = (int*)(ws + OFF_IDX);
  float* xt   = ws + OFF_XT;
  ushort* Phi = (ushort*)(ws + OFF_PHI);

  hipMemsetAsync(sums, 0, 256 * sizeof(float), stream);

  k_prep <<<256, 256, 0, stream>>>(x, w1, xx, xt, Phi, A, Cc);
  k_knn8 <<<512, 512, 0, stream>>>(Phi, xx, xt, A, Cc, b1, idx, sums);
  k_l2m5 <<<512, 256, 0, stream>>>(A, Cc, idx, sums, b1, g1, be1, w2, b2,
                                   ymax, ymin, sums + 128);
  k_out2 <<<256, 256, 0, stream>>>(ymax, ymin, sums + 128, g2, be2, out);
}

// Round 14
// 153.694 us; speedup vs baseline: 1.0838x; 1.0838x over previous
//
#include <hip/hip_runtime.h>
#include <float.h>

#define B_ 4
#define C_ 64
#define N_ 4096
#define O_ 64
#define K_ 20
#define EPS_ 1e-5f

typedef float f32x4 __attribute__((ext_vector_type(4)));
typedef short s16x8 __attribute__((ext_vector_type(8)));

union Frag { uint4 u; s16x8 s; };

// ws layout (in float slots)
#define OFF_XX   ((size_t)0)              // 16384
#define OFF_A    ((size_t)16384)          // 1048576
#define OFF_CC   ((size_t)1064960)        // 1048576
#define OFF_YMAX ((size_t)2113536)        // 1048576  (xt lives here until k_l2m5)
#define OFF_YMIN ((size_t)3162112)        // 1048576  (Phi lives here until k_l2m5)
#define OFF_SUMS ((size_t)4210688)        // 256
#define OFF_IDX  ((size_t)4211200)        // 327680 ints
#define OFF_XT   OFF_YMAX
#define OFF_PHI  OFF_YMIN

__device__ inline ushort f2bf(float f) {
  uint u = __float_as_uint(f);
  return (ushort)((u + 0x7fffu + ((u >> 16) & 1u)) >> 16);
}
__device__ inline float bf2f(ushort h) { return __uint_as_float(((uint)h) << 16); }

// ------ K0: fused prep: xx, xt, Phi, A, Cc from one x read ------------
__global__ __launch_bounds__(256) void k_prep(const float* __restrict__ x,
                                              const float* __restrict__ w1,
                                              float* __restrict__ xx,
                                              float* __restrict__ xt,
                                              ushort* __restrict__ Phi,
                                              float* __restrict__ A,
                                              float* __restrict__ Cc) {
  __shared__ float lds[64 * 65];
  __shared__ ushort ldsW[32 * 512];
  const int tid = threadIdx.x;
  const int lane = tid & 63, w = tid >> 6;
  const int b = blockIdx.x >> 6;
  const int n0 = (blockIdx.x & 63) << 6;
  const int bN = b << 12;

  {
    const int nl = tid & 63;
    const int rbase = (tid >> 6) * 16;
#pragma unroll
    for (int r = 0; r < 16; ++r) {
      int c = rbase + r;
      lds[c * 65 + nl] = x[((size_t)(b * 64 + c)) * N_ + n0 + nl];
    }
  }
  __syncthreads();

  {
    int p = tid >> 2, c0 = (tid & 3) << 4;
#pragma unroll
    for (int q = 0; q < 4; ++q) {
      float4 v;
      v.x = lds[(c0 + q * 4 + 0) * 65 + p];
      v.y = lds[(c0 + q * 4 + 1) * 65 + p];
      v.z = lds[(c0 + q * 4 + 2) * 65 + p];
      v.w = lds[(c0 + q * 4 + 3) * 65 + p];
      *(float4*)(xt + ((size_t)(bN + n0 + p)) * 64 + c0 + q * 4) = v;
    }
  }

  Frag xph[2], xpl[2];
  {
    const int nloc = w * 16 + (lane & 15);
    const int gnt = (n0 >> 4) + w;
#pragma unroll
    for (int kt = 0; kt < 2; ++kt) {
      int cbase = kt * 32 + ((lane >> 4) << 3);
      ushort hi[8], lo[8];
#pragma unroll
      for (int e = 0; e < 8; ++e) {
        float v = lds[(cbase + e) * 65 + nloc];
        ushort h = f2bf(v);
        float l = v - bf2f(h);
        hi[e] = h;
        lo[e] = f2bf(l);
      }
      size_t base = ((size_t)((b * 256 + gnt) * 2 + kt)) * 512 + lane * 8;
      uint4 uh, ul;
      uh.x = hi[0] | ((uint)hi[1] << 16); uh.y = hi[2] | ((uint)hi[3] << 16);
      uh.z = hi[4] | ((uint)hi[5] << 16); uh.w = hi[6] | ((uint)hi[7] << 16);
      ul.x = lo[0] | ((uint)lo[1] << 16); ul.y = lo[2] | ((uint)lo[3] << 16);
      ul.z = lo[4] | ((uint)lo[5] << 16); ul.w = lo[6] | ((uint)lo[7] << 16);
      *(uint4*)(Phi + base) = uh;
      xph[kt].u = uh;
      xpl[kt].u = ul;
    }
  }

  {
    const int l = tid & 63;
    const int sel = tid >> 6, mat = sel & 1, kt = sel >> 1;
#pragma unroll
    for (int ot = 0; ot < 4; ++ot) {
      const int o = ot * 16 + (l & 15);
      uint hw[8], lw[8];
#pragma unroll
      for (int e = 0; e < 8; ++e) {
        int c = kt * 32 + (l >> 4) * 8 + e;
        float wa = w1[o * 128 + c];
        float v = mat ? (w1[o * 128 + 64 + c] - wa) : wa;
        ushort hb = f2bf(v);
        float lv = v - bf2f(hb);
        hw[e] = hb;
        lw[e] = f2bf(lv);
      }
      uint4 uh, ul;
      uh.x = hw[0] | (hw[1] << 16); uh.y = hw[2] | (hw[3] << 16);
      uh.z = hw[4] | (hw[5] << 16); uh.w = hw[6] | (hw[7] << 16);
      ul.x = lw[0] | (lw[1] << 16); ul.y = lw[2] | (lw[3] << 16);
      ul.z = lw[4] | (lw[5] << 16); ul.w = lw[6] | (lw[7] << 16);
      int fb = (mat * 4 + ot) * 4 + kt * 2;
      *(uint4*)(&ldsW[(size_t)(fb + 0) * 512 + l * 8]) = uh;
      *(uint4*)(&ldsW[(size_t)(fb + 1) * 512 + l * 8]) = ul;
    }
  }

  if (tid < 64) {
    float acc = 0.f;
#pragma unroll
    for (int c = 0; c < 64; ++c) {
      float v = lds[c * 65 + tid];
      acc = fmaf(v, v, acc);
    }
    xx[bN + n0 + tid] = acc;
  }
  __syncthreads();

#pragma unroll
  for (int mat = 0; mat < 2; ++mat) {
    float* outp = mat ? Cc : A;
#pragma unroll
    for (int ot = 0; ot < 4; ++ot) {
      int fb = (mat * 4 + ot) * 4;
      Frag bh0, bl0, bh1, bl1;
      bh0.u = *(const uint4*)(&ldsW[(size_t)(fb + 0) * 512 + lane * 8]);
      bl0.u = *(const uint4*)(&ldsW[(size_t)(fb + 1) * 512 + lane * 8]);
      bh1.u = *(const uint4*)(&ldsW[(size_t)(fb + 2) * 512 + lane * 8]);
      bl1.u = *(const uint4*)(&ldsW[(size_t)(fb + 3) * 512 + lane * 8]);
      f32x4 acc = {0.f, 0.f, 0.f, 0.f};
      acc = __builtin_amdgcn_mfma_f32_16x16x32_bf16(xph[0].s, bh0.s, acc, 0, 0, 0);
      acc = __builtin_amdgcn_mfma_f32_16x16x32_bf16(xph[1].s, bh1.s, acc, 0, 0, 0);
      acc = __builtin_amdgcn_mfma_f32_16x16x32_bf16(xph[0].s, bl0.s, acc, 0, 0, 0);
      acc = __builtin_amdgcn_mfma_f32_16x16x32_bf16(xph[1].s, bl1.s, acc, 0, 0, 0);
      acc = __builtin_amdgcn_mfma_f32_16x16x32_bf16(xpl[0].s, bh0.s, acc, 0, 0, 0);
      acc = __builtin_amdgcn_mfma_f32_16x16x32_bf16(xpl[1].s, bh1.s, acc, 0, 0, 0);
#pragma unroll
      for (int r = 0; r < 4; ++r) {
        int ploc = w * 16 + ((lane >> 4) << 2) + r;
        outp[(size_t)(bN + n0 + ploc) * 64 + ot * 16 + (lane & 15)] = acc[r];
      }
    }
  }
}

// ------ K1: kNN. Hi-only both passes (margin 2.0), depth-3 pipelines,
// XCD swizzle, exact fp32 refine, fused BN1 stats. 512 blocks x 512 thr.
// (round-10 proven version, verbatim)
__global__ __launch_bounds__(512, 4) void k_knn8(
    const ushort* __restrict__ Phi,
    const float* __restrict__ xx, const float* __restrict__ xt,
    const float* __restrict__ A, const float* __restrict__ Cc,
    const float* __restrict__ b1, int* __restrict__ idxout,
    float* __restrict__ sums) {
  __shared__ float pool[4096];
  __shared__ float xxi[32];
  __shared__ float Tsh[32];
  __shared__ uint  cnt[32];
  __shared__ int   cand[32 * 64];

  const int tid = threadIdx.x;
  const int lane = tid & 63, w = tid >> 6;
  const int col = lane & 15, g4 = (lane >> 4) << 2;
  const int obid = (blockIdx.x & 7) * 64 + (blockIdx.x >> 3);
  const int b = obid >> 7;
  const int i0 = (obid & 127) << 5;
  const int bN = b << 12;
  if (tid < 32) { xxi[tid] = xx[bN + i0 + tid]; cnt[tid] = 0; }

  const ushort* Pb = Phi + (size_t)b * 262144 + lane * 8;
  const float*  xb = xx + bN + col;

  Frag ahi[2][2];
#pragma unroll
  for (int isub = 0; isub < 2; ++isub) {
    int nt = (i0 >> 4) + isub;
#pragma unroll
    for (int kt = 0; kt < 2; ++kt)
      ahi[isub][kt].u = *(const uint4*)(Phi + ((size_t)((b * 256 + nt) * 2 + kt)) * 512 + lane * 8);
  }
  float xxr[8];
#pragma unroll
  for (int isub = 0; isub < 2; ++isub)
#pragma unroll
    for (int r = 0; r < 4; ++r)
      xxr[isub * 4 + r] = xx[bN + i0 + isub * 16 + g4 + r];

  struct BT { Frag h0, h1; float xxj; };

  float c1[8];
#pragma unroll
  for (int r = 0; r < 8; ++r) c1[r] = FLT_MAX;

  auto hi0 = [&](const BT& t) {
    __builtin_amdgcn_s_setprio(1);
#pragma unroll
    for (int isub = 0; isub < 2; ++isub) {
      f32x4 acc = {0.f, 0.f, 0.f, 0.f};
      acc = __builtin_amdgcn_mfma_f32_16x16x32_bf16(ahi[isub][0].s, t.h0.s, acc, 0, 0, 0);
      acc = __builtin_amdgcn_mfma_f32_16x16x32_bf16(ahi[isub][1].s, t.h1.s, acc, 0, 0, 0);
#pragma unroll
      for (int r = 0; r < 4; ++r) {
        float d = fmaf(-2.f, acc[r], xxr[isub * 4 + r]) + t.xxj;
        c1[isub * 4 + r] = fminf(c1[isub * 4 + r], d);
      }
    }
    __builtin_amdgcn_s_setprio(0);
  };

  {
    const ushort* p0 = Pb + (size_t)w * 1024;
    const ushort* p1 = p0 + 8192;
    const ushort* p2 = p0 + 16384;
    const float* x0 = xb + w * 16;
    const float* x1 = x0 + 128;
    const float* x2 = x0 + 256;
    BT t0, t1, t2;
    t0.h0.u = *(const uint4*)(p0); t0.h1.u = *(const uint4*)(p0 + 512); t0.xxj = *x0;
    t1.h0.u = *(const uint4*)(p1); t1.h1.u = *(const uint4*)(p1 + 512); t1.xxj = *x1;
    t2.h0.u = *(const uint4*)(p2); t2.h1.u = *(const uint4*)(p2 + 512); t2.xxj = *x2;
    for (int g = 0; g < 10; ++g) {
      hi0(t0);
      p0 += 24576; x0 += 384;
      t0.h0.u = *(const uint4*)(p0); t0.h1.u = *(const uint4*)(p0 + 512); t0.xxj = *x0;
      hi0(t1);
      p1 += 24576; x1 += 384;
      t1.h0.u = *(const uint4*)(p1); t1.h1.u = *(const uint4*)(p1 + 512); t1.xxj = *x1;
      hi0(t2);
      p2 += 24576; x2 += 384;
      if (g < 9) { t2.h0.u = *(const uint4*)(p2); t2.h1.u = *(const uint4*)(p2 + 512); t2.xxj = *x2; }
    }
    hi0(t0);   // s = 30
    hi0(t1);   // s = 31
  }
#pragma unroll
  for (int isub = 0; isub < 2; ++isub)
#pragma unroll
    for (int r = 0; r < 4; ++r)
      pool[(isub * 16 + g4 + r) * 128 + w * 16 + col] = c1[isub * 4 + r];
  __syncthreads();

  // threshold: 20-round min-pop over 128 cell minima (4 rows/wave).
  // margin 2.0 covers 2x hi-only err (each <= ~2*2^-8*|xi||xj| <= ~0.96)
#pragma unroll
  for (int rr = 0; rr < 4; ++rr) {
    const int row = w * 4 + rr;
    float lo = pool[row * 128 + lane];
    float hi = pool[row * 128 + 64 + lane];
    float a = fminf(lo, hi);
    hi = fmaxf(lo, hi);
    lo = a;
    float m = 0.f;
    for (int t = 0; t < 20; ++t) {
      m = lo;
#pragma unroll
      for (int mm = 1; mm < 64; mm <<= 1) m = fminf(m, __shfl_xor(m, mm, 64));
      if (lo == m) { lo = hi; hi = FLT_MAX; }
    }
    if (lane == 0) Tsh[row] = m + 2.0f;
  }
  __syncthreads();
  float tr[8];
#pragma unroll
  for (int isub = 0; isub < 2; ++isub)
#pragma unroll
    for (int r = 0; r < 4; ++r) tr[isub * 4 + r] = Tsh[isub * 16 + g4 + r];

  auto comp1 = [&](int js, const BT& t) {
    const int jme = js * 16 + col;
    __builtin_amdgcn_s_setprio(1);
#pragma unroll
    for (int isub = 0; isub < 2; ++isub) {
      f32x4 acc = {0.f, 0.f, 0.f, 0.f};
      acc = __builtin_amdgcn_mfma_f32_16x16x32_bf16(ahi[isub][0].s, t.h0.s, acc, 0, 0, 0);
      acc = __builtin_amdgcn_mfma_f32_16x16x32_bf16(ahi[isub][1].s, t.h1.s, acc, 0, 0, 0);
#pragma unroll
      for (int r = 0; r < 4; ++r) {
        float d = fmaf(-2.f, acc[r], xxr[isub * 4 + r]) + t.xxj;
        if (d <= tr[isub * 4 + r]) {
          int row = isub * 16 + g4 + r;
          uint pos = atomicAdd(&cnt[row], 1u);
          if (pos < 64) cand[row * 64 + pos] = jme;
        }
      }
    }
    __builtin_amdgcn_s_setprio(0);
  };
  {
    const ushort* p0 = Pb + (size_t)w * 1024;
    const ushort* p1 = p0 + 8192;
    const ushort* p2 = p0 + 16384;
    const float* x0 = xb + w * 16;
    const float* x1 = x0 + 128;
    const float* x2 = x0 + 256;
    BT t0, t1, t2;
    t0.h0.u = *(const uint4*)(p0); t0.h1.u = *(const uint4*)(p0 + 512); t0.xxj = *x0;
    t1.h0.u = *(const uint4*)(p1); t1.h1.u = *(const uint4*)(p1 + 512); t1.xxj = *x1;
    t2.h0.u = *(const uint4*)(p2); t2.h1.u = *(const uint4*)(p2 + 512); t2.xxj = *x2;
    int js0 = w, js1 = w + 8, js2 = w + 16;
    for (int g = 0; g < 10; ++g) {
      comp1(js0, t0);
      js0 += 24; p0 += 24576; x0 += 384;
      t0.h0.u = *(const uint4*)(p0); t0.h1.u = *(const uint4*)(p0 + 512); t0.xxj = *x0;
      comp1(js1, t1);
      js1 += 24; p1 += 24576; x1 += 384;
      t1.h0.u = *(const uint4*)(p1); t1.h1.u = *(const uint4*)(p1 + 512); t1.xxj = *x1;
      comp1(js2, t2);
      js2 += 24; p2 += 24576; x2 += 384;
      if (g < 9) { t2.h0.u = *(const uint4*)(p2); t2.h1.u = *(const uint4*)(p2 + 512); t2.xxj = *x2; }
    }
    comp1(js0, t0);   // s = 30
    comp1(js1, t1);   // s = 31
  }
  __syncthreads();

  // ---------- exact fp32 refine + bitonic top-20 + fused BN1 stats --------
  const float b1r = b1[lane];
  float s = 0.f, ssq = 0.f;
  for (int rr = 0; rr < 4; ++rr) {
    const int row = w * 4 + rr;
    const int nc = (int)min(cnt[row], 64u);
    unsigned long long key = ~0ULL;
    if (lane < nc) {
      int j = cand[row * 64 + lane];
      const float* xj = xt + ((size_t)bN + j) * 64;
      const float* xic = xt + ((size_t)bN + i0 + row) * 64;
      float dot = 0.f;
#pragma unroll 8
      for (int c = 0; c < 64; ++c) dot = fmaf(xic[c], xj[c], dot);
      float dex = (xxi[row] - 2.f * dot) + xx[bN + j];
      uint fb = __float_as_uint(dex);
      fb = (fb & 0x80000000u) ? ~fb : (fb | 0x80000000u);
      key = (((unsigned long long)fb) << 32) | (uint)j;
    }
#pragma unroll
    for (int k2 = 2; k2 <= 64; k2 <<= 1) {
#pragma unroll
      for (int mm = k2 >> 1; mm >= 1; mm >>= 1) {
        uint klo = (uint)key, khi = (uint)(key >> 32);
        uint olo = __shfl_xor((int)klo, mm, 64);
        uint ohi = __shfl_xor((int)khi, mm, 64);
        unsigned long long o = (((unsigned long long)ohi) << 32) | olo;
        bool up = ((lane & k2) == 0);
        bool lowhalf = ((lane & mm) == 0);
        bool keepmin = (up == lowhalf);
        key = keepmin ? (key < o ? key : o) : (key > o ? key : o);
      }
    }
    int myj = (int)(uint)key;
    if (lane < 20) idxout[((size_t)bN + i0 + row) * 20 + lane] = myj;

    float ccv = Cc[((size_t)bN + i0 + row) * 64 + lane] + b1r;
    int jk[20];
#pragma unroll
    for (int k = 0; k < 20; ++k) jk[k] = __shfl(myj, k, 64);
    float av[20];
#pragma unroll
    for (int k = 0; k < 20; ++k) av[k] = A[((size_t)bN + jk[k]) * 64 + lane];
#pragma unroll
    for (int k = 0; k < 20; ++k) {
      float v = av[k] + ccv;
      s += v;
      ssq = fmaf(v, v, ssq);
    }
  }
  __syncthreads();
  pool[w * 64 + lane] = s;
  pool[512 + w * 64 + lane] = ssq;
  __syncthreads();
  if (tid < 64) {
    float S = 0.f, Q = 0.f;
#pragma unroll
    for (int q = 0; q < 8; ++q) {
      S += pool[q * 64 + tid];
      Q += pool[512 + q * 64 + tid];
    }
    atomicAdd(&sums[tid], S);
    atomicAdd(&sums[64 + tid], Q);
  }
}

// ------ K5: MFMA layer-2 with fin1 folded in (per-block ST1 + w2 pack).
// 512 blocks x 256 thr, 8 pts/wave, XCD swizzle.
__global__ __launch_bounds__(256, 2) void k_l2m5(
    const float* __restrict__ A, const float* __restrict__ Cc,
    const int* __restrict__ idx, const float* __restrict__ sums,
    const float* __restrict__ b1, const float* __restrict__ g1,
    const float* __restrict__ be1, const float* __restrict__ w2,
    const float* __restrict__ b2,
    float* __restrict__ ymax, float* __restrict__ ymin,
    float* __restrict__ sums2) {
  __shared__ float red2[512];
  __shared__ float st1sh[128];
  const int tid = threadIdx.x;
  const int lane = tid & 63, w = tid >> 6;
  const int g = lane >> 4, col = lane & 15;
  const int obid = (blockIdx.x & 7) * 64 + (blockIdx.x >> 3);

  // fin1 folded: BN1 scale/shift from sums (complete after k_knn8 kernel)
  if (tid < 64) {
    const float E = 327680.f;
    float m = sums[tid] / E;
    float var = fmaxf(sums[64 + tid] / E - m * m, 0.f);
    float sc = g1[tid] / sqrtf(var + EPS_);
    st1sh[tid] = sc;
    st1sh[64 + tid] = be1[tid] + (b1[tid] - m) * sc;
  }

  // per-lane w2 fragment pack (replaces w2p global)
  Frag wh[4][2], wl[4][2];
#pragma unroll
  for (int ot = 0; ot < 4; ++ot) {
#pragma unroll
    for (int kt = 0; kt < 2; ++kt) {
      const float* wr = w2 + (ot * 16 + col) * 64 + kt * 32 + g * 8;
      float4 v0 = *(const float4*)(wr);
      float4 v1 = *(const float4*)(wr + 4);
      float vv[8] = {v0.x, v0.y, v0.z, v0.w, v1.x, v1.y, v1.z, v1.w};
      uint hw[8], lw[8];
#pragma unroll
      for (int e = 0; e < 8; ++e) {
        ushort hb = f2bf(vv[e]);
        hw[e] = hb;
        lw[e] = f2bf(vv[e] - bf2f(hb));
      }
      uint4 uh, ul;
      uh.x = hw[0] | (hw[1] << 16); uh.y = hw[2] | (hw[3] << 16);
      uh.z = hw[4] | (hw[5] << 16); uh.w = hw[6] | (hw[7] << 16);
      ul.x = lw[0] | (lw[1] << 16); ul.y = lw[2] | (lw[3] << 16);
      ul.z = lw[4] | (lw[5] << 16); ul.w = lw[6] | (lw[7] << 16);
      wh[ot][kt].u = uh;
      wl[ot][kt].u = ul;
    }
  }
  __syncthreads();

  float S1v[2][8], T1v[2][8];
#pragma unroll
  for (int kt = 0; kt < 2; ++kt) {
    int c0 = kt * 32 + g * 8;
#pragma unroll
    for (int e = 0; e < 8; ++e) {
      S1v[kt][e] = st1sh[c0 + e];
      T1v[kt][e] = st1sh[64 + c0 + e];
    }
  }
  float b2r[4];
#pragma unroll
  for (int ot = 0; ot < 4; ++ot) b2r[ot] = b2[ot * 16 + col];

  float ps[4] = {0.f, 0.f, 0.f, 0.f}, pss[4] = {0.f, 0.f, 0.f, 0.f};

  for (int rep = 0; rep < 4; ++rep) {
    const int p0 = ((obid * 4 + w) * 4 + rep) * 2;
    const int bbase = (p0 >> 12) << 12;

    Frag hh[2][2][2];
#pragma unroll
    for (int pt = 0; pt < 2; ++pt) {
      const int p = p0 + pt;
      const float* Cp = Cc + (size_t)p * 64;
#pragma unroll
      for (int t = 0; t < 2; ++t) {
        int kk = t * 16 + col;
        kk = kk > 19 ? 19 : kk;
        int j = idx[p * 20 + kk];
        const float* Ap = A + ((size_t)(bbase + j)) * 64;
#pragma unroll
        for (int kt = 0; kt < 2; ++kt) {
          int c0 = kt * 32 + g * 8;
          float4 a0 = *(const float4*)(Ap + c0);
          float4 a1 = *(const float4*)(Ap + c0 + 4);
          float4 q0 = *(const float4*)(Cp + c0);
          float4 q1 = *(const float4*)(Cp + c0 + 4);
          float hv[8];
          hv[0] = fmaxf(0.f, fmaf(a0.x + q0.x, S1v[kt][0], T1v[kt][0]));
          hv[1] = fmaxf(0.f, fmaf(a0.y + q0.y, S1v[kt][1], T1v[kt][1]));
          hv[2] = fmaxf(0.f, fmaf(a0.z + q0.z, S1v[kt][2], T1v[kt][2]));
          hv[3] = fmaxf(0.f, fmaf(a0.w + q0.w, S1v[kt][3], T1v[kt][3]));
          hv[4] = fmaxf(0.f, fmaf(a1.x + q1.x, S1v[kt][4], T1v[kt][4]));
          hv[5] = fmaxf(0.f, fmaf(a1.y + q1.y, S1v[kt][5], T1v[kt][5]));
          hv[6] = fmaxf(0.f, fmaf(a1.z + q1.z, S1v[kt][6], T1v[kt][6]));
          hv[7] = fmaxf(0.f, fmaf(a1.w + q1.w, S1v[kt][7], T1v[kt][7]));
          uint4 uh;
          uh.x = f2bf(hv[0]) | ((uint)f2bf(hv[1]) << 16);
          uh.y = f2bf(hv[2]) | ((uint)f2bf(hv[3]) << 16);
          uh.z = f2bf(hv[4]) | ((uint)f2bf(hv[5]) << 16);
          uh.w = f2bf(hv[6]) | ((uint)f2bf(hv[7]) << 16);
          hh[pt][t][kt].u = uh;
        }
      }
    }

    float mx[2][4], mn[2][4];
#pragma unroll
    for (int pt = 0; pt < 2; ++pt)
#pragma unroll
      for (int ot = 0; ot < 4; ++ot) { mx[pt][ot] = -FLT_MAX; mn[pt][ot] = FLT_MAX; }

    __builtin_amdgcn_s_setprio(1);
#pragma unroll
    for (int ot = 0; ot < 4; ++ot) {
#pragma unroll
      for (int pt = 0; pt < 2; ++pt) {
        f32x4 accA = {0.f, 0.f, 0.f, 0.f};
        accA = __builtin_amdgcn_mfma_f32_16x16x32_bf16(hh[pt][0][0].s, wh[ot][0].s, accA, 0, 0, 0);
        accA = __builtin_amdgcn_mfma_f32_16x16x32_bf16(hh[pt][0][1].s, wh[ot][1].s, accA, 0, 0, 0);
        accA = __builtin_amdgcn_mfma_f32_16x16x32_bf16(hh[pt][0][0].s, wl[ot][0].s, accA, 0, 0, 0);
        accA = __builtin_amdgcn_mfma_f32_16x16x32_bf16(hh[pt][0][1].s, wl[ot][1].s, accA, 0, 0, 0);
        f32x4 accB = {0.f, 0.f, 0.f, 0.f};
        accB = __builtin_amdgcn_mfma_f32_16x16x32_bf16(hh[pt][1][0].s, wh[ot][0].s, accB, 0, 0, 0);
        accB = __builtin_amdgcn_mfma_f32_16x16x32_bf16(hh[pt][1][1].s, wh[ot][1].s, accB, 0, 0, 0);
        accB = __builtin_amdgcn_mfma_f32_16x16x32_bf16(hh[pt][1][0].s, wl[ot][0].s, accB, 0, 0, 0);
        accB = __builtin_amdgcn_mfma_f32_16x16x32_bf16(hh[pt][1][1].s, wl[ot][1].s, accB, 0, 0, 0);
#pragma unroll
        for (int r = 0; r < 4; ++r) {
          float y = accA[r] + b2r[ot];
          mx[pt][ot] = fmaxf(mx[pt][ot], y);
          mn[pt][ot] = fminf(mn[pt][ot], y);
          ps[ot] += y;
          pss[ot] = fmaf(y, y, pss[ot]);
        }
        if (g == 0) {
#pragma unroll
          for (int r = 0; r < 4; ++r) {
            float y = accB[r] + b2r[ot];
            mx[pt][ot] = fmaxf(mx[pt][ot], y);
            mn[pt][ot] = fminf(mn[pt][ot], y);
            ps[ot] += y;
            pss[ot] = fmaf(y, y, pss[ot]);
          }
        }
      }
    }
    __builtin_amdgcn_s_setprio(0);

#pragma unroll
    for (int pt = 0; pt < 2; ++pt) {
#pragma unroll
      for (int ot = 0; ot < 4; ++ot) {
        float v = mx[pt][ot];
        v = fmaxf(v, __shfl_xor(v, 16, 64));
        v = fmaxf(v, __shfl_xor(v, 32, 64));
        mx[pt][ot] = v;
        float u = mn[pt][ot];
        u = fminf(u, __shfl_xor(u, 16, 64));
        u = fminf(u, __shfl_xor(u, 32, 64));
        mn[pt][ot] = u;
      }
      float wmx = mx[pt][0], wmn = mn[pt][0];
      if (g == 1) { wmx = mx[pt][1]; wmn = mn[pt][1]; }
      if (g == 2) { wmx = mx[pt][2]; wmn = mn[pt][2]; }
      if (g == 3) { wmx = mx[pt][3]; wmn = mn[pt][3]; }
      ymax[(size_t)(p0 + pt) * 64 + lane] = wmx;
      ymin[(size_t)(p0 + pt) * 64 + lane] = wmn;
    }
  }

#pragma unroll
  for (int ot = 0; ot < 4; ++ot) {
    float s = ps[ot];
    s += __shfl_xor(s, 16, 64);
    s += __shfl_xor(s, 32, 64);
    ps[ot] = s;
    float q = pss[ot];
    q += __shfl_xor(q, 16, 64);
    q += __shfl_xor(q, 32, 64);
    pss[ot] = q;
  }
  float sv = ps[0], qv = pss[0];
  if (g == 1) { sv = ps[1]; qv = pss[1]; }
  if (g == 2) { sv = ps[2]; qv = pss[2]; }
  if (g == 3) { sv = ps[3]; qv = pss[3]; }
  red2[w * 64 + lane] = sv;
  red2[256 + w * 64 + lane] = qv;
  __syncthreads();
  if (tid < 64) {
    float S = red2[tid] + red2[64 + tid] + red2[128 + tid] + red2[192 + tid];
    float Q = red2[256 + tid] + red2[320 + tid] + red2[384 + tid] + red2[448 + tid];
    atomicAdd(&sums2[tid], S);
    atomicAdd(&sums2[64 + tid], Q);
  }
}

// ------ K6: epilogue with fin2 folded in + LDS transpose ------------------
__global__ __launch_bounds__(256) void k_out2(const float* __restrict__ ymax,
                                              const float* __restrict__ ymin,
                                              const float* __restrict__ sums2,
                                              const float* __restrict__ g2,
                                              const float* __restrict__ be2,
                                              float* __restrict__ out) {
  __shared__ float tl[64 * 65];
  const int tid = threadIdx.x;
  const int b = blockIdx.x >> 6;
  const int n0 = (blockIdx.x & 63) << 6;
  {
    const int o = tid & 63, pr = tid >> 6;
    // fin2 folded: BN2 scale/shift from sums2 (complete after k_l2m5 kernel)
    const float E = 327680.f;
    float m = sums2[o] / E;
    float var = fmaxf(sums2[64 + o] / E - m * m, 0.f);
    float s = g2[o] / sqrtf(var + EPS_);
    float tt = be2[o] - m * s;
#pragma unroll
    for (int q = 0; q < 16; ++q) {
      int pl = pr + q * 4;
      size_t p = ((size_t)(b << 12)) + n0 + pl;
      float vmax = ymax[p * 64 + o];
      float vmin = ymin[p * 64 + o];
      float v = (s >= 0.f) ? vmax : vmin;
      tl[o * 65 + pl] = fmaxf(0.f, fmaf(v, s, tt));
    }
  }
  __syncthreads();
  {
    const int nl = tid & 63, orow = tid >> 6;
#pragma unroll
    for (int q = 0; q < 16; ++q) {
      int oo = orow + q * 4;
      out[((size_t)(b * 64 + oo)) * N_ + n0 + nl] = tl[oo * 65 + nl];
    }
  }
}

extern "C" void kernel_launch(void* const* d_in, const int* in_sizes, int n_in,
                              void* d_out, int out_size, void* d_ws, size_t ws_size,
                              hipStream_t stream) {
  const float* x   = (const float*)d_in[0];
  const float* w1  = (const float*)d_in[1];
  const float* b1  = (const float*)d_in[2];
  const float* g1  = (const float*)d_in[3];
  const float* be1 = (const float*)d_in[4];
  const float* w2  = (const float*)d_in[5];
  const float* b2  = (const float*)d_in[6];
  const float* g2  = (const float*)d_in[7];
  const float* be2 = (const float*)d_in[8];
  float* out = (float*)d_out;
  float* ws = (float*)d_ws;

  float* xx   = ws + OFF_XX;
  float* A    = ws + OFF_A;
  float* Cc   = ws + OFF_CC;
  float* ymax = ws + OFF_YMAX;
  float* ymin = ws + OFF_YMIN;
  float* sums = ws + OFF_SUMS;   // [sum1|sumsq1|sum2|sumsq2], 256 floats
  int*   idx  = (int*)(ws + OFF_IDX);
  float* xt   = ws + OFF_XT;
  ushort* Phi = (ushort*)(ws + OFF_PHI);

  hipMemsetAsync(sums, 0, 256 * sizeof(float), stream);

  k_prep <<<256, 256, 0, stream>>>(x, w1, xx, xt, Phi, A, Cc);
  k_knn8 <<<512, 512, 0, stream>>>(Phi, xx, xt, A, Cc, b1, idx, sums);
  k_l2m5 <<<512, 256, 0, stream>>>(A, Cc, idx, sums, b1, g1, be1, w2, b2,
                                   ymax, ymin, sums + 128);
  k_out2 <<<256, 256, 0, stream>>>(ymax, ymin, sums + 128, g2, be2, out);
}